// Round 10
// baseline (264.380 us; speedup 1.0000x reference)
//
#include <hip/hip_runtime.h>
#include <hip/hip_bf16.h>

#define C_DIM 100000
#define N_ROW 512
#define K_DIM 512
#define OUT_HALF 51200000  // N_ROW * C_DIM

#define SCALE_F 64.0f
#define ALPHA_F 0.1f
#define COS_M_F 0.87758256189037276f
#define SIN_M_F 0.47942553860420301f
#define THRESH_F (-0.87758256189037276f)
#define MM_F 0.23971276930210151f

// ws layout (bytes)
#define WS_ASW 0u
#define WS_TARGET 524288u
#define WS_CTM 526336u
#define WS_FTL 528384u
#define WS_TNEW 530432u
#define WS_INVN 532480u                       // 100352 f32 = 401408 B
#define WS_BSW 1048576ull
#define BSW_BYTES (1564ull * 65536ull)        // 1564 sub-strips x 64 KiB
#define WS_NEED (WS_BSW + BSW_BYTES)

typedef __attribute__((ext_vector_type(8))) short short8;
typedef __attribute__((ext_vector_type(4))) float f32x4;
typedef __attribute__((ext_vector_type(2))) int i32x2;

static __device__ __forceinline__ unsigned short f2bf(float f) {
  union { float f; unsigned u; } x; x.f = f;
  unsigned r = x.u + 0x7fffu + ((x.u >> 16) & 1u);
  return (unsigned short)(r >> 16);
}

// ---------------------------------------------------------------------------
// N1: normalize embedding rows, write bf16 A in MFMA-fragment-ready layout.
// ---------------------------------------------------------------------------
__global__ __launch_bounds__(64) void prep_emb(const float* __restrict__ emb,
                                               unsigned short* __restrict__ Asw) {
  const int m = blockIdx.x;
  const int t = threadIdx.x;
  const float* row = emb + (size_t)m * K_DIM;
  float ss = 0.f;
#pragma unroll
  for (int d = 0; d < 8; ++d) { float v = row[t + 64 * d]; ss += v * v; }
#pragma unroll
  for (int off = 32; off > 0; off >>= 1) ss += __shfl_xor(ss, off, 64);
  const float inv = rsqrtf(ss);
  const int s = t >> 2, g = t & 3;
  short8 pack;
#pragma unroll
  for (int j = 0; j < 8; ++j) {
    int k = 32 * s + 4 * g + (j & 3) + 16 * (j >> 2);
    pack[j] = (short)f2bf(row[k] * inv);
  }
  size_t idx = ((size_t)(s * 32 + (m >> 4)) * 64 + (m & 15) + 16 * g) * 8;
  *(short8*)(Asw + idx) = pack;
}

// ---------------------------------------------------------------------------
// N3: per-row target logit in f32
// ---------------------------------------------------------------------------
__global__ __launch_bounds__(64) void target_k(const float* __restrict__ emb,
                                               const float* __restrict__ Kmat,
                                               const int* __restrict__ labels,
                                               float* __restrict__ target) {
  const int i = blockIdx.x;
  const int t = threadIdx.x;
  const int lab = labels[i];
  const float* row = emb + (size_t)i * K_DIM;
  float dot = 0.f, ess = 0.f, kss = 0.f;
#pragma unroll
  for (int d0 = 0; d0 < 8; ++d0) {
    int d = t + 64 * d0;
    float e = row[d];
    float k = Kmat[(size_t)d * C_DIM + lab];
    dot += e * k; ess += e * e; kss += k * k;
  }
#pragma unroll
  for (int off = 32; off > 0; off >>= 1) {
    dot += __shfl_xor(dot, off, 64);
    ess += __shfl_xor(ess, off, 64);
    kss += __shfl_xor(kss, off, 64);
  }
  if (t == 0) {
    float tg = dot * rsqrtf(ess) * rsqrtf(kss);
    tg = fminf(1.f, fmaxf(-1.f, tg));
    target[i] = tg;
  }
}

// ---------------------------------------------------------------------------
// N4: t_new, per-row cos_theta_m and final_target_logit
// ---------------------------------------------------------------------------
__global__ __launch_bounds__(512) void rowdata_k(const float* __restrict__ target,
                                                 const float* __restrict__ t_in,
                                                 float* __restrict__ ctm,
                                                 float* __restrict__ ftl,
                                                 float* __restrict__ tnew) {
  __shared__ float red[512];
  const int i = threadIdx.x;
  const float tg = target[i];
  red[i] = tg;
  __syncthreads();
  for (int s = 256; s > 0; s >>= 1) {
    if (i < s) red[i] += red[i + s];
    __syncthreads();
  }
  const float t_new = red[0] * (1.0f / 512.0f) * ALPHA_F + (1.f - ALPHA_F) * t_in[0];
  const float st = sqrtf(fmaxf(0.f, 1.f - tg * tg));
  const float cm = tg * COS_M_F - st * SIN_M_F;
  ctm[i] = cm;
  ftl[i] = (tg > THRESH_F) ? cm : (tg - MM_F);
  if (i == 0) tnew[0] = t_new;
}

// ---------------------------------------------------------------------------
// K1: column norms + f32->bf16 conversion into FRAGMENT-MAJOR layout BswT
// (exact R8 version). A GEMM lane l loads its whole 16x16x32 B-fragment as
// ONE contiguous short8.
// ---------------------------------------------------------------------------
__global__ __launch_bounds__(512) void colnorm_convert(
    const float* __restrict__ Kmat, unsigned short* __restrict__ Bsw,
    float* __restrict__ invn_g) {
  __shared__ f32x4 red[8][64];
  const int t = threadIdx.x;
  const int q = t & 63;
  const int rg = t >> 6;
  const int c0 = blockIdx.x * 256;
  const int cg = c0 + q * 4;
  const bool cok = (cg < C_DIM);
  f32x4 ssq = (f32x4){0.f, 0.f, 0.f, 0.f};
  char* const sbase = (char*)Bsw + (size_t)(cg >> 6) * 65536 +
                      (size_t)((cg & 63) >> 4) * 1024 + (size_t)((q & 3) * 4) * 16;
#pragma unroll
  for (int s2 = 0; s2 < 2; ++s2) {
    const int s = rg * 2 + s2;
#pragma unroll
    for (int g = 0; g < 4; ++g) {
      f32x4 v[8];
      const int rlo = 32 * s + 4 * g;
#pragma unroll
      for (int i = 0; i < 4; ++i) {
        v[i] = (f32x4){0.f, 0.f, 0.f, 0.f};
        v[4 + i] = (f32x4){0.f, 0.f, 0.f, 0.f};
        if (cok) {
          v[i] = __builtin_nontemporal_load(
              (const f32x4*)(Kmat + (size_t)(rlo + i) * C_DIM + cg));
          v[4 + i] = __builtin_nontemporal_load(
              (const f32x4*)(Kmat + (size_t)(rlo + 16 + i) * C_DIM + cg));
        }
      }
#pragma unroll
      for (int i = 0; i < 8; ++i) ssq += v[i] * v[i];
      char* dst = sbase + (size_t)s * 4096 + (size_t)(16 * g) * 16;
#pragma unroll
      for (int cc = 0; cc < 4; ++cc) {
        short8 pk;
#pragma unroll
        for (int i = 0; i < 8; ++i) pk[i] = (short)f2bf(v[i][cc]);
        *(short8*)(dst + cc * 16) = pk;
      }
    }
  }
  red[rg][q] = ssq;
  __syncthreads();
  if (t < 64) {
    f32x4 s = red[0][t];
#pragma unroll
    for (int g = 1; g < 8; ++g) s += red[g][t];
    f32x4 iv;
#pragma unroll
    for (int j = 0; j < 4; ++j) iv[j] = rsqrtf(fmaxf(s[j], 1e-30f));
    *(f32x4*)&invn_g[c0 + t * 4] = iv;
  }
}

// ---------------------------------------------------------------------------
// K2 (R10): EXACT R8 structure -- free-running no-LDS MFMA loop, block =
// 64 rows x 256 cols, LDS-staged 1 KB-contiguous row-segment stores --
// with ONE change: PLAIN stores instead of nontemporal. Theory: NT bypasses
// L2 write-combining, so 1 KB wave bursts degrade to 64 B DRAM transactions
// (~3 TB/s); plain stores take the fillBuffer path (6.8 TB/s measured).
// ---------------------------------------------------------------------------
__global__ __launch_bounds__(256, 4) void gemm_wide(
    const unsigned short* __restrict__ Bsw,
    const unsigned short* __restrict__ Asw,
    const float* __restrict__ invn_g,
    const float* __restrict__ ctm_a,
    const float* __restrict__ ftl_a,
    const float* __restrict__ tnew_p,
    const int* __restrict__ labels,
    float* __restrict__ out) {
  __shared__ float Ep[32][260];  // 33280 B; +4 pad keeps LDS writes 2-way

  const int tid = threadIdx.x;
  const int wv = tid >> 6;   // 0..3
  const int lane = tid & 63;

  // decode: xcd = bid&7; each XCD owns a contiguous chunk of strips; the 8
  // m-blocks of one strip are adjacent bids on the SAME xcd (bid stride 8).
  const int bid = blockIdx.x;
  const int xcd = bid & 7;
  const int n = bid >> 3;            // 0..391
  const int strip = xcd * 49 + (n >> 3);
  const int mblock = n & 7;
  if (strip >= 391) return;          // 8 masked blocks (grid 3136)
  const int c0 = strip * 256;
  const int mb0 = mblock * 64;

  const unsigned short* bs = Bsw + (size_t)(strip * 4 + wv) * 32768;

  f32x4 acc[4][4];
#pragma unroll
  for (int i = 0; i < 4; ++i)
#pragma unroll
    for (int j = 0; j < 4; ++j) acc[i][j] = (f32x4){0.f, 0.f, 0.f, 0.f};

  // ---- free-running MFMA K-loop (verbatim R8) ----
#pragma unroll 4
  for (int s = 0; s < 16; ++s) {
    short8 X[4], Y[4];
#pragma unroll
    for (int cs = 0; cs < 4; ++cs)
      X[cs] = *(const short8*)(bs + (size_t)(s * 2048 + cs * 512 + lane * 8));
#pragma unroll
    for (int ms = 0; ms < 4; ++ms) {
      const int msub = mblock * 4 + ms;  // 16-row unit within 512 rows
      Y[ms] = *(const short8*)(Asw + (size_t)((s * 32 + msub) * 64 + lane) * 8);
    }
#pragma unroll
    for (int cs = 0; cs < 4; ++cs)
#pragma unroll
      for (int ms = 0; ms < 4; ++ms)
        acc[cs][ms] =
            __builtin_amdgcn_mfma_f32_16x16x32_bf16(X[cs], Y[ms], acc[cs][ms], 0, 0, 0);
  }

  // ---- epilogue: LDS-staged, row-contiguous 1 KB stores (PLAIN, not NT) ----
  const float t_new = tnew_p[0];
  const int cq = (lane >> 4) * 4;

#pragma unroll
  for (int h = 0; h < 2; ++h) {  // row halves: rows mb0+32h .. +31
    float ctm2[2], ftl2[2];
    int lab2[2];
#pragma unroll
    for (int u = 0; u < 2; ++u) {
      const int m = mb0 + h * 32 + u * 16 + (lane & 15);
      ctm2[u] = ctm_a[m];
      ftl2[u] = ftl_a[m];
      lab2[u] = labels[m];
    }
#pragma unroll
    for (int o = 0; o < 2; ++o) {  // 0: ct, 1: origin_cos
      __syncthreads();             // guard LDS buffer reuse
#pragma unroll
      for (int u = 0; u < 2; ++u) {
        const int ms = h * 2 + u;
#pragma unroll
        for (int cs = 0; cs < 4; ++cs) {
          const int cl = wv * 64 + cs * 16 + cq;  // block-local col
          const int c = c0 + cl;
          const f32x4 a = acc[cs][ms];
          const f32x4 inv4 = *(const f32x4*)&invn_g[c0 + cl];
          f32x4 vv;
#pragma unroll
          for (int r = 0; r < 4; ++r) {
            float cosv = a[r] * inv4[r];
            cosv = fminf(1.f, fmaxf(-1.f, cosv));
            if (o) {
              vv[r] = cosv * SCALE_F;
            } else {
              float hard = cosv * (t_new + cosv);
              float v = (cosv > ctm2[u]) ? hard : cosv;
              if (c + r == lab2[u]) v = ftl2[u];
              vv[r] = v * SCALE_F;
            }
          }
          *(f32x4*)&Ep[u * 16 + (lane & 15)][cl] = vv;
        }
      }
      __syncthreads();
      // stream 32 rows x 1 KB: each wave-instruction = 1 KB CONTIGUOUS
      float* const obase = out + (o ? (size_t)OUT_HALF : (size_t)0);
      const int c = c0 + lane * 4;
      if (c < C_DIM) {  // 4-col granular (C%4==0)
#pragma unroll
        for (int i = 0; i < 8; ++i) {
          const int rl = wv * 8 + i;  // 0..31
          const int m = mb0 + h * 32 + rl;
          const f32x4 v = *(const f32x4*)&Ep[rl][lane * 4];
          *(f32x4*)(obase + (size_t)m * C_DIM + c) = v;  // PLAIN store
        }
      }
    }
  }
}

// ---------------------------------------------------------------------------
// Fallback fused kernel if ws too small (never taken in practice).
// ---------------------------------------------------------------------------
__global__ __launch_bounds__(512, 4) void gemm_ep_fused(
    const float* __restrict__ Kmat,
    const unsigned short* __restrict__ Asw,
    const float* __restrict__ ctm_a,
    const float* __restrict__ ftl_a,
    const float* __restrict__ tnew_p,
    const int* __restrict__ labels,
    float* __restrict__ out) {
  __shared__ unsigned short Xl[16 * 2048];
  __shared__ f32x4 ssq_sh[32][16];
  __shared__ float invn[64];

  const int tid = threadIdx.x;
  const int c0 = blockIdx.x * 64;
  const int q = tid & 15;
  const int r0 = tid >> 4;
  const int cg = c0 + q * 4;
  const bool cok = (cg < C_DIM);

  f32x4 ssq = (f32x4){0.f, 0.f, 0.f, 0.f};
  char* const wbase = (char*)&Xl[0] + (q >> 2) * 1024 + (r0 * 16 + (q & 3) * 4) * 2;
#pragma unroll
  for (int i = 0; i < 16; ++i) {
    f32x4 v = (f32x4){0.f, 0.f, 0.f, 0.f};
    if (cok)
      v = __builtin_nontemporal_load(
          (const f32x4*)(Kmat + (size_t)(r0 + 32 * i) * C_DIM + cg));
    ssq += v * v;
    i32x2 p;
    p[0] = (int)((unsigned)f2bf(v[0]) | ((unsigned)f2bf(v[1]) << 16));
    p[1] = (int)((unsigned)f2bf(v[2]) | ((unsigned)f2bf(v[3]) << 16));
    *(i32x2*)(wbase + i * 4096) = p;
  }
  ssq_sh[r0][q] = ssq;
  __syncthreads();
  if (tid < 16) {
    f32x4 ssum = (f32x4){0.f, 0.f, 0.f, 0.f};
#pragma unroll
    for (int r = 0; r < 32; ++r) ssum += ssq_sh[r][tid];
    f32x4 iv;
#pragma unroll
    for (int j = 0; j < 4; ++j) iv[j] = rsqrtf(fmaxf(ssum[j], 1e-30f));
    *(f32x4*)&invn[tid * 4] = iv;
  }
  __syncthreads();

  const int wv = tid >> 6;
  const int lane = tid & 63;

  f32x4 acc[4][4];
#pragma unroll
  for (int i = 0; i < 4; ++i)
#pragma unroll
    for (int j = 0; j < 4; ++j) acc[i][j] = (f32x4){0.f, 0.f, 0.f, 0.f};

#pragma unroll
  for (int s = 0; s < 16; ++s) {
    short8 Y[4];
#pragma unroll
    for (int j = 0; j < 4; ++j)
      Y[j] = *(const short8*)(Asw + (size_t)((s * 32 + wv * 4 + j) * 64 + lane) * 8);

    short8 X[4];
#pragma unroll
    for (int cs = 0; cs < 4; ++cs) {
      short8 x;
#pragma unroll
      for (int j = 0; j < 8; ++j) {
        int k = 4 * (lane >> 4) + (j & 3) + 16 * (j >> 2);
        x[j] = (short)Xl[s * 2048 + cs * 512 + k * 16 + (lane & 15)];
      }
      X[cs] = x;
    }

#pragma unroll
    for (int cs = 0; cs < 4; ++cs)
#pragma unroll
      for (int ms = 0; ms < 4; ++ms)
        acc[cs][ms] =
            __builtin_amdgcn_mfma_f32_16x16x32_bf16(X[cs], Y[ms], acc[cs][ms], 0, 0, 0);
  }

  const float t_new = tnew_p[0];
  const int mb = (wv << 6) + (lane & 15);
  float ctm_r[4], ftl_r[4];
  int lab_r[4];
#pragma unroll
  for (int j = 0; j < 4; ++j) {
    int m = mb + 16 * j;
    ctm_r[j] = ctm_a[m];
    ftl_r[j] = ftl_a[m];
    lab_r[j] = labels[m];
  }
  const int cq = (lane >> 4) * 4;

#pragma unroll
  for (int cs = 0; cs < 4; ++cs) {
    const int cl = cs * 16 + cq;
    const int c = c0 + cl;
    if (c >= C_DIM) continue;
    const f32x4 inv4 = *(const f32x4*)&invn[cl];
#pragma unroll
    for (int ms = 0; ms < 4; ++ms) {
      const int m = mb + 16 * ms;
      f32x4 a = acc[cs][ms];
      f32x4 og, ct;
#pragma unroll
      for (int r = 0; r < 4; ++r) {
        float cosv = a[r] * inv4[r];
        cosv = fminf(1.f, fmaxf(-1.f, cosv));
        og[r] = cosv * SCALE_F;
        float hard = cosv * (t_new + cosv);
        float v = (cosv > ctm_r[ms]) ? hard : cosv;
        if (c + r == lab_r[ms]) v = ftl_r[ms];
        ct[r] = v * SCALE_F;
      }
      const size_t o = (size_t)m * C_DIM + c;
      *(f32x4*)(out + o) = ct;
      *(f32x4*)(out + OUT_HALF + o) = og;
    }
  }
}

extern "C" void kernel_launch(void* const* d_in, const int* in_sizes, int n_in,
                              void* d_out, int out_size, void* d_ws, size_t ws_size,
                              hipStream_t stream) {
  const float* emb = (const float*)d_in[0];
  const float* Kmat = (const float*)d_in[1];
  const float* t_in = (const float*)d_in[2];
  const int* labels = (const int*)d_in[3];
  float* out = (float*)d_out;

  char* ws = (char*)d_ws;
  unsigned short* Asw = (unsigned short*)(ws + WS_ASW);
  float* target = (float*)(ws + WS_TARGET);
  float* ctm = (float*)(ws + WS_CTM);
  float* ftl = (float*)(ws + WS_FTL);
  float* tnew = (float*)(ws + WS_TNEW);

  prep_emb<<<512, 64, 0, stream>>>(emb, Asw);
  target_k<<<512, 64, 0, stream>>>(emb, Kmat, labels, target);
  rowdata_k<<<1, 512, 0, stream>>>(target, t_in, ctm, ftl, tnew);

  if (ws_size >= (size_t)WS_NEED) {
    unsigned short* Bsw = (unsigned short*)(ws + WS_BSW);
    float* invn_g = (float*)(ws + WS_INVN);
    colnorm_convert<<<391, 512, 0, stream>>>(Kmat, Bsw, invn_g);
    // 8 XCDs x 49 strip-slots x 8 m-blocks = 3136 (8 masked; 391 strips)
    gemm_wide<<<3136, 256, 0, stream>>>(Bsw, Asw, invn_g, ctm, ftl, tnew, labels, out);
  } else {
    gemm_ep_fused<<<1563, 512, 0, stream>>>(Kmat, Asw, ctm, ftl, tnew, labels, out);
  }
}

// Round 11
// 242.504 us; speedup vs baseline: 1.0902x; 1.0902x over previous
//
#include <hip/hip_runtime.h>
#include <hip/hip_bf16.h>

#define C_DIM 100000
#define N_ROW 512
#define K_DIM 512
#define OUT_HALF 51200000  // N_ROW * C_DIM

#define SCALE_F 64.0f
#define ALPHA_F 0.1f
#define COS_M_F 0.87758256189037276f
#define SIN_M_F 0.47942553860420301f
#define THRESH_F (-0.87758256189037276f)
#define MM_F 0.23971276930210151f

// ws layout (bytes)
#define WS_ASW 0u
#define WS_TARGET 524288u
#define WS_CTM 526336u
#define WS_FTL 528384u
#define WS_TNEW 530432u
#define WS_INVN 532480u                       // 100352 f32 = 401408 B
#define WS_BSW 1048576ull
#define BSW_BYTES (1564ull * 65536ull)        // 1564 sub-strips x 64 KiB
#define WS_NEED (WS_BSW + BSW_BYTES)

typedef __attribute__((ext_vector_type(8))) short short8;
typedef __attribute__((ext_vector_type(4))) float f32x4;
typedef __attribute__((ext_vector_type(2))) int i32x2;

static __device__ __forceinline__ unsigned short f2bf(float f) {
  union { float f; unsigned u; } x; x.f = f;
  unsigned r = x.u + 0x7fffu + ((x.u >> 16) & 1u);
  return (unsigned short)(r >> 16);
}

// ---------------------------------------------------------------------------
// N1: normalize embedding rows, write bf16 A in MFMA-fragment-ready layout.
// ---------------------------------------------------------------------------
__global__ __launch_bounds__(64) void prep_emb(const float* __restrict__ emb,
                                               unsigned short* __restrict__ Asw) {
  const int m = blockIdx.x;
  const int t = threadIdx.x;
  const float* row = emb + (size_t)m * K_DIM;
  float ss = 0.f;
#pragma unroll
  for (int d = 0; d < 8; ++d) { float v = row[t + 64 * d]; ss += v * v; }
#pragma unroll
  for (int off = 32; off > 0; off >>= 1) ss += __shfl_xor(ss, off, 64);
  const float inv = rsqrtf(ss);
  const int s = t >> 2, g = t & 3;
  short8 pack;
#pragma unroll
  for (int j = 0; j < 8; ++j) {
    int k = 32 * s + 4 * g + (j & 3) + 16 * (j >> 2);
    pack[j] = (short)f2bf(row[k] * inv);
  }
  size_t idx = ((size_t)(s * 32 + (m >> 4)) * 64 + (m & 15) + 16 * g) * 8;
  *(short8*)(Asw + idx) = pack;
}

// ---------------------------------------------------------------------------
// N3: per-row target logit in f32
// ---------------------------------------------------------------------------
__global__ __launch_bounds__(64) void target_k(const float* __restrict__ emb,
                                               const float* __restrict__ Kmat,
                                               const int* __restrict__ labels,
                                               float* __restrict__ target) {
  const int i = blockIdx.x;
  const int t = threadIdx.x;
  const int lab = labels[i];
  const float* row = emb + (size_t)i * K_DIM;
  float dot = 0.f, ess = 0.f, kss = 0.f;
#pragma unroll
  for (int d0 = 0; d0 < 8; ++d0) {
    int d = t + 64 * d0;
    float e = row[d];
    float k = Kmat[(size_t)d * C_DIM + lab];
    dot += e * k; ess += e * e; kss += k * k;
  }
#pragma unroll
  for (int off = 32; off > 0; off >>= 1) {
    dot += __shfl_xor(dot, off, 64);
    ess += __shfl_xor(ess, off, 64);
    kss += __shfl_xor(kss, off, 64);
  }
  if (t == 0) {
    float tg = dot * rsqrtf(ess) * rsqrtf(kss);
    tg = fminf(1.f, fmaxf(-1.f, tg));
    target[i] = tg;
  }
}

// ---------------------------------------------------------------------------
// N4: t_new, per-row cos_theta_m and final_target_logit
// ---------------------------------------------------------------------------
__global__ __launch_bounds__(512) void rowdata_k(const float* __restrict__ target,
                                                 const float* __restrict__ t_in,
                                                 float* __restrict__ ctm,
                                                 float* __restrict__ ftl,
                                                 float* __restrict__ tnew) {
  __shared__ float red[512];
  const int i = threadIdx.x;
  const float tg = target[i];
  red[i] = tg;
  __syncthreads();
  for (int s = 256; s > 0; s >>= 1) {
    if (i < s) red[i] += red[i + s];
    __syncthreads();
  }
  const float t_new = red[0] * (1.0f / 512.0f) * ALPHA_F + (1.f - ALPHA_F) * t_in[0];
  const float st = sqrtf(fmaxf(0.f, 1.f - tg * tg));
  const float cm = tg * COS_M_F - st * SIN_M_F;
  ctm[i] = cm;
  ftl[i] = (tg > THRESH_F) ? cm : (tg - MM_F);
  if (i == 0) tnew[0] = t_new;
}

// ---------------------------------------------------------------------------
// K1 v3: column norms + f32->bf16 conversion into FRAGMENT-MAJOR Bsw.
// SAME Bsw layout as R8 (GEMM untouched), NEW write path: per 128-row
// k-chunk, the 64 KB fragment-major image is staged in LDS (XOR-swizzled
// to spread ds_write_b128 banks), then copied out LINEARLY: each
// wave-instruction NT-stores 1 KB fully contiguous, each substrip region
// written sequentially. Reads stay 1 KB-contiguous-per-row NT loads.
// ---------------------------------------------------------------------------
__global__ __launch_bounds__(512) void colnorm_convert(
    const float* __restrict__ Kmat, unsigned short* __restrict__ Bsw,
    float* __restrict__ invn_g) {
  __shared__ __align__(16) unsigned char stage[65536];  // 64 KiB chunk image
  __shared__ f32x4 red[8][64];                          // 8 KiB

  const int t = threadIdx.x;
  const int q = t & 63;   // col quad within 256-col panel
  const int rg = t >> 6;  // wave id 0..7
  const int c0 = blockIdx.x * 256;
  const int cg = c0 + q * 4;
  const bool cok = (cg < C_DIM);  // float4 fully in-bounds (C%4==0)
  const int sub = q >> 4;         // substrip 0..3
  const int cs = (q >> 2) & 3;    // 16-col subtile within substrip
  const unsigned lbase =
      (unsigned)(sub * 16384 + cs * 1024 + (4 * (q & 3)) * 16);

  f32x4 ssq = (f32x4){0.f, 0.f, 0.f, 0.f};

  for (int chunk = 0; chunk < 4; ++chunk) {
    // ---- read (1 KB/row coalesced) + pack into LDS fragment-major ----
#pragma unroll
    for (int i2 = 0; i2 < 2; ++i2) {
      const int u = i2 * 8 + rg;     // 0..15: (s_loc, g) unit
      const int s_loc = u >> 2;      // 0..3
      const int g = u & 3;           // fragment k-group
      const int rlo = chunk * 128 + s_loc * 32 + g * 4;
      f32x4 v[8];
#pragma unroll
      for (int i = 0; i < 4; ++i) {
        v[i] = (f32x4){0.f, 0.f, 0.f, 0.f};
        v[4 + i] = (f32x4){0.f, 0.f, 0.f, 0.f};
        if (cok) {
          v[i] = __builtin_nontemporal_load(
              (const f32x4*)(Kmat + (size_t)(rlo + i) * C_DIM + cg));
          v[4 + i] = __builtin_nontemporal_load(
              (const f32x4*)(Kmat + (size_t)(rlo + 16 + i) * C_DIM + cg));
        }
      }
#pragma unroll
      for (int i = 0; i < 8; ++i) ssq += v[i] * v[i];
      const unsigned base =
          lbase + (unsigned)(s_loc * 4096 + (16 * g) * 16);
#pragma unroll
      for (int cc = 0; cc < 4; ++cc) {
        short8 pk;
#pragma unroll
        for (int i = 0; i < 8; ++i) pk[i] = (short)f2bf(v[i][cc]);
        unsigned off = base + (unsigned)(cc * 16);
        off ^= ((off >> 10) & 3u) << 4;  // bank-spread swizzle
        *(short8*)&stage[off] = pk;
      }
    }
    __syncthreads();
    // ---- copy-out: linear, 1 KB contiguous per wave-instruction, NT ----
#pragma unroll
    for (int p = 0; p < 8; ++p) {
      const unsigned lin = (unsigned)(p * 8192 + t * 16);
      unsigned off = lin ^ (((lin >> 10) & 3u) << 4);
      const f32x4 v = *(const f32x4*)&stage[off];
      const int osub = (int)(lin >> 14);
      const unsigned x = lin & 16383u;
      char* dst = (char*)Bsw + (size_t)(blockIdx.x * 4 + osub) * 65536 +
                  (size_t)chunk * 16384 + x;
      __builtin_nontemporal_store(v, (f32x4*)dst);
    }
    __syncthreads();
  }

  // ---- per-column sum-of-squares -> inverse norms ----
  red[rg][q] = ssq;
  __syncthreads();
  if (t < 64) {
    f32x4 s = red[0][t];
#pragma unroll
    for (int g = 1; g < 8; ++g) s += red[g][t];
    f32x4 iv;
#pragma unroll
    for (int j = 0; j < 4; ++j) iv[j] = rsqrtf(fmaxf(s[j], 1e-30f));
    *(f32x4*)&invn_g[c0 + t * 4] = iv;
  }
}

// ---------------------------------------------------------------------------
// K2: EXACT R8 gemm_wide (verified best): free-running no-LDS MFMA loop,
// block = 64 rows x 256 cols, LDS-staged 1 KB-contiguous NT stores.
// ---------------------------------------------------------------------------
__global__ __launch_bounds__(256, 4) void gemm_wide(
    const unsigned short* __restrict__ Bsw,
    const unsigned short* __restrict__ Asw,
    const float* __restrict__ invn_g,
    const float* __restrict__ ctm_a,
    const float* __restrict__ ftl_a,
    const float* __restrict__ tnew_p,
    const int* __restrict__ labels,
    float* __restrict__ out) {
  __shared__ float Ep[32][260];  // 33280 B; +4 pad keeps LDS writes 2-way

  const int tid = threadIdx.x;
  const int wv = tid >> 6;   // 0..3
  const int lane = tid & 63;

  const int bid = blockIdx.x;
  const int xcd = bid & 7;
  const int n = bid >> 3;            // 0..391
  const int strip = xcd * 49 + (n >> 3);
  const int mblock = n & 7;
  if (strip >= 391) return;          // 8 masked blocks (grid 3136)
  const int c0 = strip * 256;
  const int mb0 = mblock * 64;

  const unsigned short* bs = Bsw + (size_t)(strip * 4 + wv) * 32768;

  f32x4 acc[4][4];
#pragma unroll
  for (int i = 0; i < 4; ++i)
#pragma unroll
    for (int j = 0; j < 4; ++j) acc[i][j] = (f32x4){0.f, 0.f, 0.f, 0.f};

  // ---- free-running MFMA K-loop (verbatim R8) ----
#pragma unroll 4
  for (int s = 0; s < 16; ++s) {
    short8 X[4], Y[4];
#pragma unroll
    for (int cs = 0; cs < 4; ++cs)
      X[cs] = *(const short8*)(bs + (size_t)(s * 2048 + cs * 512 + lane * 8));
#pragma unroll
    for (int ms = 0; ms < 4; ++ms) {
      const int msub = mblock * 4 + ms;  // 16-row unit within 512 rows
      Y[ms] = *(const short8*)(Asw + (size_t)((s * 32 + msub) * 64 + lane) * 8);
    }
#pragma unroll
    for (int cs = 0; cs < 4; ++cs)
#pragma unroll
      for (int ms = 0; ms < 4; ++ms)
        acc[cs][ms] =
            __builtin_amdgcn_mfma_f32_16x16x32_bf16(X[cs], Y[ms], acc[cs][ms], 0, 0, 0);
  }

  // ---- epilogue: LDS-staged, row-contiguous 1 KB NT stores ----
  const float t_new = tnew_p[0];
  const int cq = (lane >> 4) * 4;

#pragma unroll
  for (int h = 0; h < 2; ++h) {  // row halves: rows mb0+32h .. +31
    float ctm2[2], ftl2[2];
    int lab2[2];
#pragma unroll
    for (int u = 0; u < 2; ++u) {
      const int m = mb0 + h * 32 + u * 16 + (lane & 15);
      ctm2[u] = ctm_a[m];
      ftl2[u] = ftl_a[m];
      lab2[u] = labels[m];
    }
#pragma unroll
    for (int o = 0; o < 2; ++o) {  // 0: ct, 1: origin_cos
      __syncthreads();             // guard LDS buffer reuse
#pragma unroll
      for (int u = 0; u < 2; ++u) {
        const int ms = h * 2 + u;
#pragma unroll
        for (int cs = 0; cs < 4; ++cs) {
          const int cl = wv * 64 + cs * 16 + cq;  // block-local col
          const int c = c0 + cl;
          const f32x4 a = acc[cs][ms];
          const f32x4 inv4 = *(const f32x4*)&invn_g[c0 + cl];
          f32x4 vv;
#pragma unroll
          for (int r = 0; r < 4; ++r) {
            float cosv = a[r] * inv4[r];
            cosv = fminf(1.f, fmaxf(-1.f, cosv));
            if (o) {
              vv[r] = cosv * SCALE_F;
            } else {
              float hard = cosv * (t_new + cosv);
              float v = (cosv > ctm2[u]) ? hard : cosv;
              if (c + r == lab2[u]) v = ftl2[u];
              vv[r] = v * SCALE_F;
            }
          }
          *(f32x4*)&Ep[u * 16 + (lane & 15)][cl] = vv;
        }
      }
      __syncthreads();
      // stream 32 rows x 1 KB: each wave-instruction = 1 KB CONTIGUOUS
      float* const obase = out + (o ? (size_t)OUT_HALF : (size_t)0);
      const int c = c0 + lane * 4;
      if (c < C_DIM) {  // 4-col granular (C%4==0)
#pragma unroll
        for (int i = 0; i < 8; ++i) {
          const int rl = wv * 8 + i;  // 0..31
          const int m = mb0 + h * 32 + rl;
          const f32x4 v = *(const f32x4*)&Ep[rl][lane * 4];
          __builtin_nontemporal_store(v, (f32x4*)(obase + (size_t)m * C_DIM + c));
        }
      }
    }
  }
}

// ---------------------------------------------------------------------------
// Fallback fused kernel if ws too small (never taken in practice).
// ---------------------------------------------------------------------------
__global__ __launch_bounds__(512, 4) void gemm_ep_fused(
    const float* __restrict__ Kmat,
    const unsigned short* __restrict__ Asw,
    const float* __restrict__ ctm_a,
    const float* __restrict__ ftl_a,
    const float* __restrict__ tnew_p,
    const int* __restrict__ labels,
    float* __restrict__ out) {
  __shared__ unsigned short Xl[16 * 2048];
  __shared__ f32x4 ssq_sh[32][16];
  __shared__ float invn[64];

  const int tid = threadIdx.x;
  const int c0 = blockIdx.x * 64;
  const int q = tid & 15;
  const int r0 = tid >> 4;
  const int cg = c0 + q * 4;
  const bool cok = (cg < C_DIM);

  f32x4 ssq = (f32x4){0.f, 0.f, 0.f, 0.f};
  char* const wbase = (char*)&Xl[0] + (q >> 2) * 1024 + (r0 * 16 + (q & 3) * 4) * 2;
#pragma unroll
  for (int i = 0; i < 16; ++i) {
    f32x4 v = (f32x4){0.f, 0.f, 0.f, 0.f};
    if (cok)
      v = __builtin_nontemporal_load(
          (const f32x4*)(Kmat + (size_t)(r0 + 32 * i) * C_DIM + cg));
    ssq += v * v;
    i32x2 p;
    p[0] = (int)((unsigned)f2bf(v[0]) | ((unsigned)f2bf(v[1]) << 16));
    p[1] = (int)((unsigned)f2bf(v[2]) | ((unsigned)f2bf(v[3]) << 16));
    *(i32x2*)(wbase + i * 4096) = p;
  }
  ssq_sh[r0][q] = ssq;
  __syncthreads();
  if (tid < 16) {
    f32x4 ssum = (f32x4){0.f, 0.f, 0.f, 0.f};
#pragma unroll
    for (int r = 0; r < 32; ++r) ssum += ssq_sh[r][tid];
    f32x4 iv;
#pragma unroll
    for (int j = 0; j < 4; ++j) iv[j] = rsqrtf(fmaxf(ssum[j], 1e-30f));
    *(f32x4*)&invn[tid * 4] = iv;
  }
  __syncthreads();

  const int wv = tid >> 6;
  const int lane = tid & 63;

  f32x4 acc[4][4];
#pragma unroll
  for (int i = 0; i < 4; ++i)
#pragma unroll
    for (int j = 0; j < 4; ++j) acc[i][j] = (f32x4){0.f, 0.f, 0.f, 0.f};

#pragma unroll
  for (int s = 0; s < 16; ++s) {
    short8 Y[4];
#pragma unroll
    for (int j = 0; j < 4; ++j)
      Y[j] = *(const short8*)(Asw + (size_t)((s * 32 + wv * 4 + j) * 64 + lane) * 8);

    short8 X[4];
#pragma unroll
    for (int cs = 0; cs < 4; ++cs) {
      short8 x;
#pragma unroll
      for (int j = 0; j < 8; ++j) {
        int k = 4 * (lane >> 4) + (j & 3) + 16 * (j >> 2);
        x[j] = (short)Xl[s * 2048 + cs * 512 + k * 16 + (lane & 15)];
      }
      X[cs] = x;
    }

#pragma unroll
    for (int cs = 0; cs < 4; ++cs)
#pragma unroll
      for (int ms = 0; ms < 4; ++ms)
        acc[cs][ms] =
            __builtin_amdgcn_mfma_f32_16x16x32_bf16(X[cs], Y[ms], acc[cs][ms], 0, 0, 0);
  }

  const float t_new = tnew_p[0];
  const int mb = (wv << 6) + (lane & 15);
  float ctm_r[4], ftl_r[4];
  int lab_r[4];
#pragma unroll
  for (int j = 0; j < 4; ++j) {
    int m = mb + 16 * j;
    ctm_r[j] = ctm_a[m];
    ftl_r[j] = ftl_a[m];
    lab_r[j] = labels[m];
  }
  const int cq = (lane >> 4) * 4;

#pragma unroll
  for (int cs = 0; cs < 4; ++cs) {
    const int cl = cs * 16 + cq;
    const int c = c0 + cl;
    if (c >= C_DIM) continue;
    const f32x4 inv4 = *(const f32x4*)&invn[cl];
#pragma unroll
    for (int ms = 0; ms < 4; ++ms) {
      const int m = mb + 16 * ms;
      f32x4 a = acc[cs][ms];
      f32x4 og, ct;
#pragma unroll
      for (int r = 0; r < 4; ++r) {
        float cosv = a[r] * inv4[r];
        cosv = fminf(1.f, fmaxf(-1.f, cosv));
        og[r] = cosv * SCALE_F;
        float hard = cosv * (t_new + cosv);
        float v = (cosv > ctm_r[ms]) ? hard : cosv;
        if (c + r == lab_r[ms]) v = ftl_r[ms];
        ct[r] = v * SCALE_F;
      }
      const size_t o = (size_t)m * C_DIM + c;
      *(f32x4*)(out + o) = ct;
      *(f32x4*)(out + OUT_HALF + o) = og;
    }
  }
}

extern "C" void kernel_launch(void* const* d_in, const int* in_sizes, int n_in,
                              void* d_out, int out_size, void* d_ws, size_t ws_size,
                              hipStream_t stream) {
  const float* emb = (const float*)d_in[0];
  const float* Kmat = (const float*)d_in[1];
  const float* t_in = (const float*)d_in[2];
  const int* labels = (const int*)d_in[3];
  float* out = (float*)d_out;

  char* ws = (char*)d_ws;
  unsigned short* Asw = (unsigned short*)(ws + WS_ASW);
  float* target = (float*)(ws + WS_TARGET);
  float* ctm = (float*)(ws + WS_CTM);
  float* ftl = (float*)(ws + WS_FTL);
  float* tnew = (float*)(ws + WS_TNEW);

  prep_emb<<<512, 64, 0, stream>>>(emb, Asw);
  target_k<<<512, 64, 0, stream>>>(emb, Kmat, labels, target);
  rowdata_k<<<1, 512, 0, stream>>>(target, t_in, ctm, ftl, tnew);

  if (ws_size >= (size_t)WS_NEED) {
    unsigned short* Bsw = (unsigned short*)(ws + WS_BSW);
    float* invn_g = (float*)(ws + WS_INVN);
    colnorm_convert<<<391, 512, 0, stream>>>(Kmat, Bsw, invn_g);
    // 8 XCDs x 49 strip-slots x 8 m-blocks = 3136 (8 masked; 391 strips)
    gemm_wide<<<3136, 256, 0, stream>>>(Bsw, Asw, invn_g, ctm, ftl, tnew, labels, out);
  } else {
    gemm_ep_fused<<<1563, 512, 0, stream>>>(Kmat, Asw, ctm, ftl, tnew, labels, out);
  }
}

// Round 12
// 230.168 us; speedup vs baseline: 1.1486x; 1.0536x over previous
//
#include <hip/hip_runtime.h>
#include <hip/hip_bf16.h>

#define C_DIM 100000
#define N_ROW 512
#define K_DIM 512
#define OUT_HALF 51200000  // N_ROW * C_DIM

#define SCALE_F 64.0f
#define ALPHA_F 0.1f
#define COS_M_F 0.87758256189037276f
#define SIN_M_F 0.47942553860420301f
#define THRESH_F (-0.87758256189037276f)
#define MM_F 0.23971276930210151f

// ws layout (bytes)
#define WS_ASW 0u
#define WS_TARGET 524288u
#define WS_CTM 526336u
#define WS_FTL 528384u
#define WS_TNEW 530432u
#define WS_INVN 532480u                       // 100352 f32 = 401408 B
#define WS_BSW 1048576ull
#define BSW_BYTES (1564ull * 65536ull)        // 1564 sub-strips x 64 KiB
#define WS_NEED (WS_BSW + BSW_BYTES)

typedef __attribute__((ext_vector_type(8))) short short8;
typedef __attribute__((ext_vector_type(4))) float f32x4;
typedef __attribute__((ext_vector_type(2))) int i32x2;

static __device__ __forceinline__ unsigned short f2bf(float f) {
  union { float f; unsigned u; } x; x.f = f;
  unsigned r = x.u + 0x7fffu + ((x.u >> 16) & 1u);
  return (unsigned short)(r >> 16);
}

// ---------------------------------------------------------------------------
// N1: normalize embedding rows, write bf16 A in MFMA-fragment-ready layout.
// ---------------------------------------------------------------------------
__global__ __launch_bounds__(64) void prep_emb(const float* __restrict__ emb,
                                               unsigned short* __restrict__ Asw) {
  const int m = blockIdx.x;
  const int t = threadIdx.x;
  const float* row = emb + (size_t)m * K_DIM;
  float ss = 0.f;
#pragma unroll
  for (int d = 0; d < 8; ++d) { float v = row[t + 64 * d]; ss += v * v; }
#pragma unroll
  for (int off = 32; off > 0; off >>= 1) ss += __shfl_xor(ss, off, 64);
  const float inv = rsqrtf(ss);
  const int s = t >> 2, g = t & 3;
  short8 pack;
#pragma unroll
  for (int j = 0; j < 8; ++j) {
    int k = 32 * s + 4 * g + (j & 3) + 16 * (j >> 2);
    pack[j] = (short)f2bf(row[k] * inv);
  }
  size_t idx = ((size_t)(s * 32 + (m >> 4)) * 64 + (m & 15) + 16 * g) * 8;
  *(short8*)(Asw + idx) = pack;
}

// ---------------------------------------------------------------------------
// N3: per-row target logit in f32
// ---------------------------------------------------------------------------
__global__ __launch_bounds__(64) void target_k(const float* __restrict__ emb,
                                               const float* __restrict__ Kmat,
                                               const int* __restrict__ labels,
                                               float* __restrict__ target) {
  const int i = blockIdx.x;
  const int t = threadIdx.x;
  const int lab = labels[i];
  const float* row = emb + (size_t)i * K_DIM;
  float dot = 0.f, ess = 0.f, kss = 0.f;
#pragma unroll
  for (int d0 = 0; d0 < 8; ++d0) {
    int d = t + 64 * d0;
    float e = row[d];
    float k = Kmat[(size_t)d * C_DIM + lab];
    dot += e * k; ess += e * e; kss += k * k;
  }
#pragma unroll
  for (int off = 32; off > 0; off >>= 1) {
    dot += __shfl_xor(dot, off, 64);
    ess += __shfl_xor(ess, off, 64);
    kss += __shfl_xor(kss, off, 64);
  }
  if (t == 0) {
    float tg = dot * rsqrtf(ess) * rsqrtf(kss);
    tg = fminf(1.f, fmaxf(-1.f, tg));
    target[i] = tg;
  }
}

// ---------------------------------------------------------------------------
// N4: t_new, per-row cos_theta_m and final_target_logit
// ---------------------------------------------------------------------------
__global__ __launch_bounds__(512) void rowdata_k(const float* __restrict__ target,
                                                 const float* __restrict__ t_in,
                                                 float* __restrict__ ctm,
                                                 float* __restrict__ ftl,
                                                 float* __restrict__ tnew) {
  __shared__ float red[512];
  const int i = threadIdx.x;
  const float tg = target[i];
  red[i] = tg;
  __syncthreads();
  for (int s = 256; s > 0; s >>= 1) {
    if (i < s) red[i] += red[i + s];
    __syncthreads();
  }
  const float t_new = red[0] * (1.0f / 512.0f) * ALPHA_F + (1.f - ALPHA_F) * t_in[0];
  const float st = sqrtf(fmaxf(0.f, 1.f - tg * tg));
  const float cm = tg * COS_M_F - st * SIN_M_F;
  ctm[i] = cm;
  ftl[i] = (tg > THRESH_F) ? cm : (tg - MM_F);
  if (i == 0) tnew[0] = t_new;
}

// ---------------------------------------------------------------------------
// K1 (R12): column norms + f32->bf16 conversion into FRAGMENT-MAJOR Bsw.
// Identical layout/addressing to R8. ONE change: the two s2-units of each
// g-group are merged so 16 f32x4 loads (256 B/thread) are in flight before
// any conversion consumes them -- 2x the MLP per wave vs R8's 8-deep batch,
// targeting the unit-level s_waitcnt stall (load batch -> 150 serial VALU).
// ---------------------------------------------------------------------------
__global__ __launch_bounds__(512) void colnorm_convert(
    const float* __restrict__ Kmat, unsigned short* __restrict__ Bsw,
    float* __restrict__ invn_g) {
  __shared__ f32x4 red[8][64];
  const int t = threadIdx.x;
  const int q = t & 63;
  const int rg = t >> 6;
  const int c0 = blockIdx.x * 256;
  const int cg = c0 + q * 4;
  const bool cok = (cg < C_DIM);
  f32x4 ssq = (f32x4){0.f, 0.f, 0.f, 0.f};
  char* const sbase = (char*)Bsw + (size_t)(cg >> 6) * 65536 +
                      (size_t)((cg & 63) >> 4) * 1024 + (size_t)((q & 3) * 4) * 16;
  const int s0 = rg * 2;  // this wave owns k-tiles s0 and s0+1
#pragma unroll
  for (int g = 0; g < 4; ++g) {
    f32x4 v[16];
    const int rlo0 = 32 * s0 + 4 * g;
    const int rlo1 = 32 * (s0 + 1) + 4 * g;
    // issue ALL 16 loads before any consumption (16-deep MLP)
#pragma unroll
    for (int i = 0; i < 4; ++i) {
      v[i] = (f32x4){0.f, 0.f, 0.f, 0.f};
      v[4 + i] = (f32x4){0.f, 0.f, 0.f, 0.f};
      v[8 + i] = (f32x4){0.f, 0.f, 0.f, 0.f};
      v[12 + i] = (f32x4){0.f, 0.f, 0.f, 0.f};
      if (cok) {
        v[i] = __builtin_nontemporal_load(
            (const f32x4*)(Kmat + (size_t)(rlo0 + i) * C_DIM + cg));
        v[4 + i] = __builtin_nontemporal_load(
            (const f32x4*)(Kmat + (size_t)(rlo0 + 16 + i) * C_DIM + cg));
        v[8 + i] = __builtin_nontemporal_load(
            (const f32x4*)(Kmat + (size_t)(rlo1 + i) * C_DIM + cg));
        v[12 + i] = __builtin_nontemporal_load(
            (const f32x4*)(Kmat + (size_t)(rlo1 + 16 + i) * C_DIM + cg));
      }
    }
#pragma unroll
    for (int i = 0; i < 16; ++i) ssq += v[i] * v[i];
    char* dst0 = sbase + (size_t)s0 * 4096 + (size_t)(16 * g) * 16;
    char* dst1 = sbase + (size_t)(s0 + 1) * 4096 + (size_t)(16 * g) * 16;
#pragma unroll
    for (int cc = 0; cc < 4; ++cc) {
      short8 pk0, pk1;
#pragma unroll
      for (int i = 0; i < 8; ++i) {
        pk0[i] = (short)f2bf(v[i][cc]);
        pk1[i] = (short)f2bf(v[8 + i][cc]);
      }
      *(short8*)(dst0 + cc * 16) = pk0;
      *(short8*)(dst1 + cc * 16) = pk1;
    }
  }
  red[rg][q] = ssq;
  __syncthreads();
  if (t < 64) {
    f32x4 s = red[0][t];
#pragma unroll
    for (int g = 1; g < 8; ++g) s += red[g][t];
    f32x4 iv;
#pragma unroll
    for (int j = 0; j < 4; ++j) iv[j] = rsqrtf(fmaxf(s[j], 1e-30f));
    *(f32x4*)&invn_g[c0 + t * 4] = iv;
  }
}

// ---------------------------------------------------------------------------
// K2: EXACT R8 gemm_wide (verified best, 225 us total): free-running no-LDS
// MFMA loop, block = 64 rows x 256 cols, LDS-staged 1 KB-contiguous NT
// stores, (256,4) = 16 waves/CU (register-pinned optimum: acc 64 AGPR +
// ~64 VGPR x 16 waves fills the unified file).
// ---------------------------------------------------------------------------
__global__ __launch_bounds__(256, 4) void gemm_wide(
    const unsigned short* __restrict__ Bsw,
    const unsigned short* __restrict__ Asw,
    const float* __restrict__ invn_g,
    const float* __restrict__ ctm_a,
    const float* __restrict__ ftl_a,
    const float* __restrict__ tnew_p,
    const int* __restrict__ labels,
    float* __restrict__ out) {
  __shared__ float Ep[32][260];  // 33280 B; +4 pad keeps LDS writes 2-way

  const int tid = threadIdx.x;
  const int wv = tid >> 6;   // 0..3
  const int lane = tid & 63;

  const int bid = blockIdx.x;
  const int xcd = bid & 7;
  const int n = bid >> 3;            // 0..391
  const int strip = xcd * 49 + (n >> 3);
  const int mblock = n & 7;
  if (strip >= 391) return;          // 8 masked blocks (grid 3136)
  const int c0 = strip * 256;
  const int mb0 = mblock * 64;

  const unsigned short* bs = Bsw + (size_t)(strip * 4 + wv) * 32768;

  f32x4 acc[4][4];
#pragma unroll
  for (int i = 0; i < 4; ++i)
#pragma unroll
    for (int j = 0; j < 4; ++j) acc[i][j] = (f32x4){0.f, 0.f, 0.f, 0.f};

  // ---- free-running MFMA K-loop ----
#pragma unroll 4
  for (int s = 0; s < 16; ++s) {
    short8 X[4], Y[4];
#pragma unroll
    for (int cs = 0; cs < 4; ++cs)
      X[cs] = *(const short8*)(bs + (size_t)(s * 2048 + cs * 512 + lane * 8));
#pragma unroll
    for (int ms = 0; ms < 4; ++ms) {
      const int msub = mblock * 4 + ms;  // 16-row unit within 512 rows
      Y[ms] = *(const short8*)(Asw + (size_t)((s * 32 + msub) * 64 + lane) * 8);
    }
#pragma unroll
    for (int cs = 0; cs < 4; ++cs)
#pragma unroll
      for (int ms = 0; ms < 4; ++ms)
        acc[cs][ms] =
            __builtin_amdgcn_mfma_f32_16x16x32_bf16(X[cs], Y[ms], acc[cs][ms], 0, 0, 0);
  }

  // ---- epilogue: LDS-staged, row-contiguous 1 KB NT stores ----
  const float t_new = tnew_p[0];
  const int cq = (lane >> 4) * 4;

#pragma unroll
  for (int h = 0; h < 2; ++h) {  // row halves: rows mb0+32h .. +31
    float ctm2[2], ftl2[2];
    int lab2[2];
#pragma unroll
    for (int u = 0; u < 2; ++u) {
      const int m = mb0 + h * 32 + u * 16 + (lane & 15);
      ctm2[u] = ctm_a[m];
      ftl2[u] = ftl_a[m];
      lab2[u] = labels[m];
    }
#pragma unroll
    for (int o = 0; o < 2; ++o) {  // 0: ct, 1: origin_cos
      __syncthreads();             // guard LDS buffer reuse
#pragma unroll
      for (int u = 0; u < 2; ++u) {
        const int ms = h * 2 + u;
#pragma unroll
        for (int cs = 0; cs < 4; ++cs) {
          const int cl = wv * 64 + cs * 16 + cq;  // block-local col
          const int c = c0 + cl;
          const f32x4 a = acc[cs][ms];
          const f32x4 inv4 = *(const f32x4*)&invn_g[c0 + cl];
          f32x4 vv;
#pragma unroll
          for (int r = 0; r < 4; ++r) {
            float cosv = a[r] * inv4[r];
            cosv = fminf(1.f, fmaxf(-1.f, cosv));
            if (o) {
              vv[r] = cosv * SCALE_F;
            } else {
              float hard = cosv * (t_new + cosv);
              float v = (cosv > ctm2[u]) ? hard : cosv;
              if (c + r == lab2[u]) v = ftl2[u];
              vv[r] = v * SCALE_F;
            }
          }
          *(f32x4*)&Ep[u * 16 + (lane & 15)][cl] = vv;
        }
      }
      __syncthreads();
      // stream 32 rows x 1 KB: each wave-instruction = 1 KB CONTIGUOUS
      float* const obase = out + (o ? (size_t)OUT_HALF : (size_t)0);
      const int c = c0 + lane * 4;
      if (c < C_DIM) {  // 4-col granular (C%4==0)
#pragma unroll
        for (int i = 0; i < 8; ++i) {
          const int rl = wv * 8 + i;  // 0..31
          const int m = mb0 + h * 32 + rl;
          const f32x4 v = *(const f32x4*)&Ep[rl][lane * 4];
          __builtin_nontemporal_store(v, (f32x4*)(obase + (size_t)m * C_DIM + c));
        }
      }
    }
  }
}

// ---------------------------------------------------------------------------
// Fallback fused kernel if ws too small (never taken in practice).
// ---------------------------------------------------------------------------
__global__ __launch_bounds__(512, 4) void gemm_ep_fused(
    const float* __restrict__ Kmat,
    const unsigned short* __restrict__ Asw,
    const float* __restrict__ ctm_a,
    const float* __restrict__ ftl_a,
    const float* __restrict__ tnew_p,
    const int* __restrict__ labels,
    float* __restrict__ out) {
  __shared__ unsigned short Xl[16 * 2048];
  __shared__ f32x4 ssq_sh[32][16];
  __shared__ float invn[64];

  const int tid = threadIdx.x;
  const int c0 = blockIdx.x * 64;
  const int q = tid & 15;
  const int r0 = tid >> 4;
  const int cg = c0 + q * 4;
  const bool cok = (cg < C_DIM);

  f32x4 ssq = (f32x4){0.f, 0.f, 0.f, 0.f};
  char* const wbase = (char*)&Xl[0] + (q >> 2) * 1024 + (r0 * 16 + (q & 3) * 4) * 2;
#pragma unroll
  for (int i = 0; i < 16; ++i) {
    f32x4 v = (f32x4){0.f, 0.f, 0.f, 0.f};
    if (cok)
      v = __builtin_nontemporal_load(
          (const f32x4*)(Kmat + (size_t)(r0 + 32 * i) * C_DIM + cg));
    ssq += v * v;
    i32x2 p;
    p[0] = (int)((unsigned)f2bf(v[0]) | ((unsigned)f2bf(v[1]) << 16));
    p[1] = (int)((unsigned)f2bf(v[2]) | ((unsigned)f2bf(v[3]) << 16));
    *(i32x2*)(wbase + i * 4096) = p;
  }
  ssq_sh[r0][q] = ssq;
  __syncthreads();
  if (tid < 16) {
    f32x4 ssum = (f32x4){0.f, 0.f, 0.f, 0.f};
#pragma unroll
    for (int r = 0; r < 32; ++r) ssum += ssq_sh[r][tid];
    f32x4 iv;
#pragma unroll
    for (int j = 0; j < 4; ++j) iv[j] = rsqrtf(fmaxf(ssum[j], 1e-30f));
    *(f32x4*)&invn[tid * 4] = iv;
  }
  __syncthreads();

  const int wv = tid >> 6;
  const int lane = tid & 63;

  f32x4 acc[4][4];
#pragma unroll
  for (int i = 0; i < 4; ++i)
#pragma unroll
    for (int j = 0; j < 4; ++j) acc[i][j] = (f32x4){0.f, 0.f, 0.f, 0.f};

#pragma unroll
  for (int s = 0; s < 16; ++s) {
    short8 Y[4];
#pragma unroll
    for (int j = 0; j < 4; ++j)
      Y[j] = *(const short8*)(Asw + (size_t)((s * 32 + wv * 4 + j) * 64 + lane) * 8);

    short8 X[4];
#pragma unroll
    for (int cs = 0; cs < 4; ++cs) {
      short8 x;
#pragma unroll
      for (int j = 0; j < 8; ++j) {
        int k = 4 * (lane >> 4) + (j & 3) + 16 * (j >> 2);
        x[j] = (short)Xl[s * 2048 + cs * 512 + k * 16 + (lane & 15)];
      }
      X[cs] = x;
    }

#pragma unroll
    for (int cs = 0; cs < 4; ++cs)
#pragma unroll
      for (int ms = 0; ms < 4; ++ms)
        acc[cs][ms] =
            __builtin_amdgcn_mfma_f32_16x16x32_bf16(X[cs], Y[ms], acc[cs][ms], 0, 0, 0);
  }

  const float t_new = tnew_p[0];
  const int mb = (wv << 6) + (lane & 15);
  float ctm_r[4], ftl_r[4];
  int lab_r[4];
#pragma unroll
  for (int j = 0; j < 4; ++j) {
    int m = mb + 16 * j;
    ctm_r[j] = ctm_a[m];
    ftl_r[j] = ftl_a[m];
    lab_r[j] = labels[m];
  }
  const int cq = (lane >> 4) * 4;

#pragma unroll
  for (int cs = 0; cs < 4; ++cs) {
    const int cl = cs * 16 + cq;
    const int c = c0 + cl;
    if (c >= C_DIM) continue;
    const f32x4 inv4 = *(const f32x4*)&invn[cl];
#pragma unroll
    for (int ms = 0; ms < 4; ++ms) {
      const int m = mb + 16 * ms;
      f32x4 a = acc[cs][ms];
      f32x4 og, ct;
#pragma unroll
      for (int r = 0; r < 4; ++r) {
        float cosv = a[r] * inv4[r];
        cosv = fminf(1.f, fmaxf(-1.f, cosv));
        og[r] = cosv * SCALE_F;
        float hard = cosv * (t_new + cosv);
        float v = (cosv > ctm_r[ms]) ? hard : cosv;
        if (c + r == lab_r[ms]) v = ftl_r[ms];
        ct[r] = v * SCALE_F;
      }
      const size_t o = (size_t)m * C_DIM + c;
      *(f32x4*)(out + o) = ct;
      *(f32x4*)(out + OUT_HALF + o) = og;
    }
  }
}

extern "C" void kernel_launch(void* const* d_in, const int* in_sizes, int n_in,
                              void* d_out, int out_size, void* d_ws, size_t ws_size,
                              hipStream_t stream) {
  const float* emb = (const float*)d_in[0];
  const float* Kmat = (const float*)d_in[1];
  const float* t_in = (const float*)d_in[2];
  const int* labels = (const int*)d_in[3];
  float* out = (float*)d_out;

  char* ws = (char*)d_ws;
  unsigned short* Asw = (unsigned short*)(ws + WS_ASW);
  float* target = (float*)(ws + WS_TARGET);
  float* ctm = (float*)(ws + WS_CTM);
  float* ftl = (float*)(ws + WS_FTL);
  float* tnew = (float*)(ws + WS_TNEW);

  prep_emb<<<512, 64, 0, stream>>>(emb, Asw);
  target_k<<<512, 64, 0, stream>>>(emb, Kmat, labels, target);
  rowdata_k<<<1, 512, 0, stream>>>(target, t_in, ctm, ftl, tnew);

  if (ws_size >= (size_t)WS_NEED) {
    unsigned short* Bsw = (unsigned short*)(ws + WS_BSW);
    float* invn_g = (float*)(ws + WS_INVN);
    colnorm_convert<<<391, 512, 0, stream>>>(Kmat, Bsw, invn_g);
    // 8 XCDs x 49 strip-slots x 8 m-blocks = 3136 (8 masked; 391 strips)
    gemm_wide<<<3136, 256, 0, stream>>>(Bsw, Asw, invn_g, ctm, ftl, tnew, labels, out);
  } else {
    gemm_ep_fused<<<1563, 512, 0, stream>>>(Kmat, Asw, ctm, ftl, tnew, labels, out);
  }
}

// Round 13
// 168.506 us; speedup vs baseline: 1.5690x; 1.3659x over previous
//
#include <hip/hip_runtime.h>
#include <hip/hip_bf16.h>

#define C_DIM 100000
#define N_ROW 512
#define K_DIM 512
#define OUT_HALF 51200000  // N_ROW * C_DIM
#define NSTRIP 391         // ceil(100000 / 256)

#define SCALE_F 64.0f
#define ALPHA_F 0.1f
#define COS_M_F 0.87758256189037276f
#define SIN_M_F 0.47942553860420301f
#define THRESH_F (-0.87758256189037276f)
#define MM_F 0.23971276930210151f

// ws layout (bytes)
#define WS_ASW 0u
#define WS_TARGET 524288u
#define WS_CTM 526336u
#define WS_FTL 528384u
#define WS_TNEW 530432u

typedef __attribute__((ext_vector_type(8))) short short8;
typedef __attribute__((ext_vector_type(4))) float f32x4;

static __device__ __forceinline__ unsigned short f2bf(float f) {
  union { float f; unsigned u; } x; x.f = f;
  unsigned r = x.u + 0x7fffu + ((x.u >> 16) & 1u);
  return (unsigned short)(r >> 16);
}

// ---------------------------------------------------------------------------
// N1: normalize embedding rows, write bf16 A in MFMA-fragment-ready layout.
// ---------------------------------------------------------------------------
__global__ __launch_bounds__(64) void prep_emb(const float* __restrict__ emb,
                                               unsigned short* __restrict__ Asw) {
  const int m = blockIdx.x;
  const int t = threadIdx.x;
  const float* row = emb + (size_t)m * K_DIM;
  float ss = 0.f;
#pragma unroll
  for (int d = 0; d < 8; ++d) { float v = row[t + 64 * d]; ss += v * v; }
#pragma unroll
  for (int off = 32; off > 0; off >>= 1) ss += __shfl_xor(ss, off, 64);
  const float inv = rsqrtf(ss);
  const int s = t >> 2, g = t & 3;
  short8 pack;
#pragma unroll
  for (int j = 0; j < 8; ++j) {
    int k = 32 * s + 4 * g + (j & 3) + 16 * (j >> 2);
    pack[j] = (short)f2bf(row[k] * inv);
  }
  size_t idx = ((size_t)(s * 32 + (m >> 4)) * 64 + (m & 15) + 16 * g) * 8;
  *(short8*)(Asw + idx) = pack;
}

// ---------------------------------------------------------------------------
// N3: per-row target logit in f32
// ---------------------------------------------------------------------------
__global__ __launch_bounds__(64) void target_k(const float* __restrict__ emb,
                                               const float* __restrict__ Kmat,
                                               const int* __restrict__ labels,
                                               float* __restrict__ target) {
  const int i = blockIdx.x;
  const int t = threadIdx.x;
  const int lab = labels[i];
  const float* row = emb + (size_t)i * K_DIM;
  float dot = 0.f, ess = 0.f, kss = 0.f;
#pragma unroll
  for (int d0 = 0; d0 < 8; ++d0) {
    int d = t + 64 * d0;
    float e = row[d];
    float k = Kmat[(size_t)d * C_DIM + lab];
    dot += e * k; ess += e * e; kss += k * k;
  }
#pragma unroll
  for (int off = 32; off > 0; off >>= 1) {
    dot += __shfl_xor(dot, off, 64);
    ess += __shfl_xor(ess, off, 64);
    kss += __shfl_xor(kss, off, 64);
  }
  if (t == 0) {
    float tg = dot * rsqrtf(ess) * rsqrtf(kss);
    tg = fminf(1.f, fmaxf(-1.f, tg));
    target[i] = tg;
  }
}

// ---------------------------------------------------------------------------
// N4: t_new, per-row cos_theta_m and final_target_logit
// ---------------------------------------------------------------------------
__global__ __launch_bounds__(512) void rowdata_k(const float* __restrict__ target,
                                                 const float* __restrict__ t_in,
                                                 float* __restrict__ ctm,
                                                 float* __restrict__ ftl,
                                                 float* __restrict__ tnew) {
  __shared__ float red[512];
  const int i = threadIdx.x;
  const float tg = target[i];
  red[i] = tg;
  __syncthreads();
  for (int s = 256; s > 0; s >>= 1) {
    if (i < s) red[i] += red[i + s];
    __syncthreads();
  }
  const float t_new = red[0] * (1.0f / 512.0f) * ALPHA_F + (1.f - ALPHA_F) * t_in[0];
  const float st = sqrtf(fmaxf(0.f, 1.f - tg * tg));
  const float cm = tg * COS_M_F - st * SIN_M_F;
  ctm[i] = cm;
  ftl[i] = (tg > THRESH_F) ? cm : (tg - MM_F);
  if (i == 0) tnew[0] = t_new;
}

// ---------------------------------------------------------------------------
// R13: FUSED gemm. R8's verified gemm_wide (64 rows x 256 cols, xcd-chunked
// strip sharing, acc[4][4], LDS-staged 1 KB-contiguous NT epilogue) with the
// Bsw reads replaced by in-kernel f32->bf16 staging:
//  - per K-step: issue 8 Kmat f32x4 loads (tile s+1) -> Y from Asw -> X via
//    contiguous short8 LDS reads -> 16 MFMA -> convert+ds_write s+1 -> barrier
//  - fragment-major LDS tile, slot^subtile XOR swizzle (conflict-free both
//    sides: write instr spreads 8 words/bank, read instr is a permutation)
//  - ssq accumulated during staging; per-block invn (colnorm kernel deleted,
//    Bsw round-trip of 204 MB eliminated; Kmat strip L2-shared by the 8
//    same-XCD m-blocks -> plain loads, NOT nontemporal)
// LDS: 33280 B union { dbuf 2 x 16384 | Ep[32][260] | red } + invn_s 1 KiB.
// ---------------------------------------------------------------------------
__global__ __launch_bounds__(256, 3) void gemm_fused(
    const float* __restrict__ Kmat,
    const unsigned short* __restrict__ Asw,
    const float* __restrict__ ctm_a,
    const float* __restrict__ ftl_a,
    const float* __restrict__ tnew_p,
    const int* __restrict__ labels,
    float* __restrict__ out) {
  __shared__ __align__(16) char lds[33280];
  __shared__ float invn_s[256];

  const int tid = threadIdx.x;
  const int wv = tid >> 6;   // wave 0..3
  const int lane = tid & 63;

  // xcd-chunked decode: a strip's 8 m-blocks are bid-stride-8 on ONE xcd
  const int bid = blockIdx.x;
  const int xcd = bid & 7;
  const int n = bid >> 3;            // 0..391
  const int strip = xcd * 49 + (n >> 3);
  const int mblock = n & 7;
  if (strip >= NSTRIP) return;       // 8 masked blocks (grid 3136)
  const int c0 = strip * 256;
  const int mb0 = mblock * 64;

  // staging role: q = lane (col quad), g = wv (fragment k-group)
  const int q = lane, g = wv;
  const int cg = c0 + q * 4;
  const bool cok = (cg < C_DIM);     // float4 fully in-bounds (C%4==0)
  const int cs_w = q >> 2;           // written subtile 0..15
  const int w0 = (q & 3) * 4;        // col-within-subtile base
  unsigned waddr[4];
#pragma unroll
  for (int cc = 0; cc < 4; ++cc)
    waddr[cc] = (unsigned)(cs_w * 1024 + ((g << 4) + ((w0 + cc) ^ cs_w)) * 16);

  f32x4 ssq = (f32x4){0.f, 0.f, 0.f, 0.f};
  f32x4 acc[4][4];
#pragma unroll
  for (int i = 0; i < 4; ++i)
#pragma unroll
    for (int j = 0; j < 4; ++j) acc[i][j] = (f32x4){0.f, 0.f, 0.f, 0.f};

  // ---- prologue: stage tile 0 into buf0 ----
  {
    f32x4 v[8];
    const float* rp = Kmat + (size_t)(4 * g) * C_DIM + cg;
#pragma unroll
    for (int i = 0; i < 4; ++i) {
      v[i] = (f32x4){0.f, 0.f, 0.f, 0.f};
      v[4 + i] = (f32x4){0.f, 0.f, 0.f, 0.f};
      if (cok) {
        v[i] = *(const f32x4*)(rp + (size_t)i * C_DIM);
        v[4 + i] = *(const f32x4*)(rp + (size_t)(16 + i) * C_DIM);
      }
    }
#pragma unroll
    for (int i = 0; i < 8; ++i) ssq += v[i] * v[i];
#pragma unroll
    for (int cc = 0; cc < 4; ++cc) {
      short8 pk;
#pragma unroll
      for (int j = 0; j < 8; ++j) pk[j] = (short)f2bf(v[j][cc]);
      *(short8*)(lds + waddr[cc]) = pk;
    }
  }
  __syncthreads();

  // ---- main K-loop: 16 steps, double-buffered, one barrier/step ----
#pragma unroll 2
  for (int s = 0; s < 16; ++s) {
    // issue next tile's 8 loads FIRST (latency hides under Y/X/MFMA)
    f32x4 nv[8];
#pragma unroll
    for (int i = 0; i < 8; ++i) nv[i] = (f32x4){0.f, 0.f, 0.f, 0.f};
    if (s < 15 && cok) {
      const float* rp = Kmat + (size_t)((s + 1) * 32 + 4 * g) * C_DIM + cg;
#pragma unroll
      for (int i = 0; i < 4; ++i) {
        nv[i] = *(const f32x4*)(rp + (size_t)i * C_DIM);
        nv[4 + i] = *(const f32x4*)(rp + (size_t)(16 + i) * C_DIM);
      }
    }

    // Y fragments (emb side) from pre-swizzled global (L2-resident)
    short8 Y[4];
#pragma unroll
    for (int ms = 0; ms < 4; ++ms) {
      const int msub = mblock * 4 + ms;
      Y[ms] = *(const short8*)(Asw + (size_t)((s * 32 + msub) * 64 + lane) * 8);
    }

    // X fragments: contiguous short8 from fragment-major LDS (swizzled slot)
    short8 X[4];
    const char* rb = lds + (s & 1) * 16384;
#pragma unroll
    for (int i = 0; i < 4; ++i) {
      const int cs = wv * 4 + i;
      X[i] = *(const short8*)(rb + cs * 1024 +
                              ((lane & 48) + ((lane & 15) ^ cs)) * 16);
    }

#pragma unroll
    for (int i = 0; i < 4; ++i)
#pragma unroll
      for (int ms = 0; ms < 4; ++ms)
        acc[i][ms] =
            __builtin_amdgcn_mfma_f32_16x16x32_bf16(X[i], Y[ms], acc[i][ms], 0, 0, 0);

    // convert + stage tile s+1 into the other buffer
    if (s < 15) {
#pragma unroll
      for (int i = 0; i < 8; ++i) ssq += nv[i] * nv[i];
      char* dst = lds + ((s + 1) & 1) * 16384;
#pragma unroll
      for (int cc = 0; cc < 4; ++cc) {
        short8 pk;
#pragma unroll
        for (int j = 0; j < 8; ++j) pk[j] = (short)f2bf(nv[j][cc]);
        *(short8*)(dst + waddr[cc]) = pk;
      }
    }
    __syncthreads();
  }

  // ---- per-block column norms (reuse buf0 area: loop is done) ----
  *(f32x4*)(lds + (g * 64 + q) * 16) = ssq;
  __syncthreads();
  if (tid < 64) {
    f32x4 ssum = *(const f32x4*)(lds + tid * 16);
#pragma unroll
    for (int gg = 1; gg < 4; ++gg)
      ssum += *(const f32x4*)(lds + (gg * 64 + tid) * 16);
    f32x4 iv;
#pragma unroll
    for (int j = 0; j < 4; ++j) iv[j] = rsqrtf(fmaxf(ssum[j], 1e-30f));
    *(f32x4*)&invn_s[tid * 4] = iv;
  }
  __syncthreads();

  // ---- epilogue: LDS-staged, row-contiguous 1 KB NT stores (verbatim R8) ----
#define EPV(r, c) (*(f32x4*)(lds + ((size_t)(r) * 260 + (c)) * 4))
  const float t_new = tnew_p[0];
  const int cq = (lane >> 4) * 4;

#pragma unroll
  for (int h = 0; h < 2; ++h) {  // row halves: rows mb0+32h .. +31
    float ctm2[2], ftl2[2];
    int lab2[2];
#pragma unroll
    for (int u = 0; u < 2; ++u) {
      const int m = mb0 + h * 32 + u * 16 + (lane & 15);
      ctm2[u] = ctm_a[m];
      ftl2[u] = ftl_a[m];
      lab2[u] = labels[m];
    }
#pragma unroll
    for (int o = 0; o < 2; ++o) {  // 0: ct, 1: origin_cos
      __syncthreads();             // guard LDS buffer reuse
#pragma unroll
      for (int u = 0; u < 2; ++u) {
        const int ms = h * 2 + u;
#pragma unroll
        for (int cs = 0; cs < 4; ++cs) {
          const int cl = wv * 64 + cs * 16 + cq;  // block-local col
          const int c = c0 + cl;
          const f32x4 a = acc[cs][ms];
          const f32x4 inv4 = *(const f32x4*)&invn_s[cl];
          f32x4 vv;
#pragma unroll
          for (int r = 0; r < 4; ++r) {
            float cosv = a[r] * inv4[r];
            cosv = fminf(1.f, fmaxf(-1.f, cosv));
            if (o) {
              vv[r] = cosv * SCALE_F;
            } else {
              float hard = cosv * (t_new + cosv);
              float v = (cosv > ctm2[u]) ? hard : cosv;
              if (c + r == lab2[u]) v = ftl2[u];
              vv[r] = v * SCALE_F;
            }
          }
          EPV(u * 16 + (lane & 15), cl) = vv;
        }
      }
      __syncthreads();
      // stream 32 rows x 1 KB: each wave-instruction = 1 KB CONTIGUOUS
      float* const obase = out + (o ? (size_t)OUT_HALF : (size_t)0);
      const int c = c0 + lane * 4;
      if (c < C_DIM) {  // 4-col granular (C%4==0)
#pragma unroll
        for (int i = 0; i < 8; ++i) {
          const int rl = wv * 8 + i;  // 0..31
          const int m = mb0 + h * 32 + rl;
          const f32x4 v = EPV(rl, lane * 4);
          __builtin_nontemporal_store(v, (f32x4*)(obase + (size_t)m * C_DIM + c));
        }
      }
    }
  }
#undef EPV
}

extern "C" void kernel_launch(void* const* d_in, const int* in_sizes, int n_in,
                              void* d_out, int out_size, void* d_ws, size_t ws_size,
                              hipStream_t stream) {
  const float* emb = (const float*)d_in[0];
  const float* Kmat = (const float*)d_in[1];
  const float* t_in = (const float*)d_in[2];
  const int* labels = (const int*)d_in[3];
  float* out = (float*)d_out;

  char* ws = (char*)d_ws;
  unsigned short* Asw = (unsigned short*)(ws + WS_ASW);
  float* target = (float*)(ws + WS_TARGET);
  float* ctm = (float*)(ws + WS_CTM);
  float* ftl = (float*)(ws + WS_FTL);
  float* tnew = (float*)(ws + WS_TNEW);

  prep_emb<<<512, 64, 0, stream>>>(emb, Asw);
  target_k<<<512, 64, 0, stream>>>(emb, Kmat, labels, target);
  rowdata_k<<<1, 512, 0, stream>>>(target, t_in, ctm, ftl, tnew);

  // 8 XCDs x 49 strip-slots x 8 m-blocks = 3136 (8 masked; 391 strips)
  gemm_fused<<<3136, 256, 0, stream>>>(Kmat, Asw, ctm, ftl, tnew, labels, out);
}